// Round 7
// baseline (299.126 us; speedup 1.0000x reference)
//
#include <hip/hip_runtime.h>
#include <hip/hip_bf16.h>

#define B_   4
#define L_   4096
#define D_   1024
#define DFF_ 4096
#define K_   2048

typedef __attribute__((ext_vector_type(8))) short bf16x8;
typedef __attribute__((ext_vector_type(4))) float f32x4;
typedef unsigned short u16;

__device__ __forceinline__ u16 f2bf(float f) {
    unsigned u = __float_as_uint(f);
    u += 0x7fffu + ((u >> 16) & 1u);          // round-to-nearest-even
    return (u16)(u >> 16);
}

__device__ __forceinline__ float gelu_fast(float v) {
    float z = 1.5957691216057308f * v * (1.0f + 0.044715f * v * v);
    float e = __builtin_amdgcn_exp2f(-1.4426950408889634f * z);
    return v * __builtin_amdgcn_rcpf(1.0f + e);
}

__device__ __forceinline__ void gload_lds16(const void* g, void* l) {
    __builtin_amdgcn_global_load_lds(
        (const __attribute__((address_space(1))) void*)g,
        (__attribute__((address_space(3))) void*)l, 16, 0, 0);
}

template<int N> __device__ __forceinline__ void wait_vm() {
    if constexpr (N == 0) asm volatile("s_waitcnt vmcnt(0)" ::: "memory");
    else if constexpr (N == 3) asm volatile("s_waitcnt vmcnt(3)" ::: "memory");
    else if constexpr (N == 4) asm volatile("s_waitcnt vmcnt(4)" ::: "memory");
    __builtin_amdgcn_sched_barrier(0);
}

// ============ fused prep: score (blocks 0..4095) + W1 transpose (4096..8191)
// ============             + W2 transpose (8192..12287)
__global__ __launch_bounds__(256) void prep_kernel(
    const float* __restrict__ x, const float* __restrict__ wr,
    const float* __restrict__ br, float* __restrict__ scores,
    const float* __restrict__ W1, const float* __restrict__ W2,
    u16* __restrict__ W1T, u16* __restrict__ W2T)
{
    __shared__ float t[32][33];
    const int bb = blockIdx.x;
    if (bb < 4096) {
        int gtid  = bb * 256 + threadIdx.x;
        int token = gtid >> 6;
        int lane  = threadIdx.x & 63;
        const float* xr = x + (size_t)token * D_;
        double acc = 0.0;
        #pragma unroll
        for (int i = 0; i < 4; ++i) {
            int off = (lane + i * 64) * 4;
            float4 xv = *(const float4*)(xr + off);
            float4 wv = *(const float4*)(wr + off);
            acc += (double)xv.x * wv.x + (double)xv.y * wv.y +
                   (double)xv.z * wv.z + (double)xv.w * wv.w;
        }
        #pragma unroll
        for (int off = 32; off > 0; off >>= 1)
            acc += __shfl_down(acc, off);
        if (lane == 0) scores[token] = (float)(acc + (double)br[0]);
        return;
    }
    const float* in; u16* outb; int RK, RN, bx, by;
    if (bb < 8192) {
        int i = bb - 4096; in = W1; outb = W1T; RK = D_; RN = DFF_;
        bx = i & 127; by = i >> 7;
    } else {
        int i = bb - 8192; in = W2; outb = W2T; RK = DFF_; RN = D_;
        bx = i & 31; by = i >> 5;
    }
    int n0 = bx * 32, k0 = by * 32;
    int tx = threadIdx.x & 31, ty = threadIdx.x >> 5;
    #pragma unroll
    for (int i = 0; i < 4; ++i)
        t[ty + 8 * i][tx] = in[(size_t)(k0 + ty + 8 * i) * RN + (n0 + tx)];
    __syncthreads();
    #pragma unroll
    for (int i = 0; i < 4; ++i)
        outb[(size_t)(n0 + ty + 8 * i) * RK + (k0 + tx)] = f2bf(t[tx][ty + 8 * i]);
}

// ============ rank (exact top-k, jax tie-break) + zero unselected out rows
__global__ __launch_bounds__(256) void rank_zero_kernel(
    const float* __restrict__ scores, int* __restrict__ sel,
    float* __restrict__ out)
{
    __shared__ float sc[L_];
    __shared__ int selLds[64];
    const int b = blockIdx.y;
    const int t = threadIdx.x;
    const float* sb = scores + b * L_;
    for (int i = t; i < L_; i += 256) sc[i] = sb[i];
    __syncthreads();
    const int tg  = t >> 2;
    const int sub = t & 3;
    const int l   = blockIdx.x * 64 + tg;
    const float s = sc[l];
    int cnt = 0;
    const float4* sc4 = (const float4*)sc;
    const int base4 = sub * 256;
    for (int j4 = 0; j4 < 256; ++j4) {
        float4 v = sc4[base4 + j4];
        int j = (base4 + j4) * 4;
        cnt += (int)((v.x > s) || (v.x == s && (j + 0) < l));
        cnt += (int)((v.y > s) || (v.y == s && (j + 1) < l));
        cnt += (int)((v.z > s) || (v.z == s && (j + 2) < l));
        cnt += (int)((v.w > s) || (v.w == s && (j + 3) < l));
    }
    cnt += __shfl_xor(cnt, 1);
    cnt += __shfl_xor(cnt, 2);
    const int issel = (cnt < K_) ? 1 : 0;
    if (sub == 0) { sel[b * L_ + l] = issel; selLds[tg] = issel; }
    __syncthreads();
    float* obase = out + ((size_t)b * L_ + (size_t)blockIdx.x * 64) * D_;
    const float4 z = make_float4(0.f, 0.f, 0.f, 0.f);
    for (int r = 0; r < 64; ++r)
        if (!selLds[r])
            *(float4*)(obase + (size_t)r * D_ + t * 4) = z;
}

// ---------------- compact selected indices (ascending) ----------------
__global__ __launch_bounds__(256) void compact_kernel(
    const int* __restrict__ sel, int* __restrict__ idx)
{
    __shared__ int psum[256];
    int b = blockIdx.x, t = threadIdx.x;
    const int* sb = sel + b * L_;
    int base = t * 16;
    int flags[16]; int c = 0;
    #pragma unroll
    for (int i = 0; i < 16; ++i) { flags[i] = sb[base + i]; c += flags[i]; }
    psum[t] = c;
    __syncthreads();
    if (t == 0) {
        int acc = 0;
        for (int j = 0; j < 256; ++j) { int v = psum[j]; psum[j] = acc; acc += v; }
    }
    __syncthreads();
    int p = psum[t];
    #pragma unroll
    for (int i = 0; i < 16; ++i)
        if (flags[i]) idx[b * K_ + (p++)] = base + i;
}

// ---------------- gather selected rows, fp32->bf16 ----------------
__global__ __launch_bounds__(256) void gather_bf16_kernel(
    const float* __restrict__ x, const int* __restrict__ idxg,
    int row0, u16* __restrict__ xsel)
{
    int rl = blockIdx.x;
    int grow = row0 + rl;
    int tok = idxg[grow];
    int bb = grow >> 11;
    const float* src = x + ((size_t)bb * L_ + (size_t)tok) * D_;
    int t = threadIdx.x;
    float4 v = *(const float4*)(src + t * 4);
    ushort4 o;
    o.x = f2bf(v.x); o.y = f2bf(v.y); o.z = f2bf(v.z); o.w = f2bf(v.w);
    *(ushort4*)(xsel + (size_t)rl * D_ + t * 4) = o;
}

// =================== unified phase-pipelined MFMA GEMM (T2+T3+T4+T5) ===================
// BN = 256 fixed, 8 waves (2M x 4N). A: [M][KD] bf16. Bm: [N][KD] bf16 (n-major).
// LDS slots are CHUNK-MAJOR ([chunk 0..3][row][8elems]) via pre-swizzled global src
// (gload_lds dst stays linear) -> frag ds_read_b128 at 16B lane-stride = conflict-free.
// BM=256: 8 phases / 2 K-tiles (16 MFMA each).  BM=128: 4 phases (16 MFMA each).
// EPI 0 (gemm1): h = bf16(gelu(acc+bias)) via LDS C-tile repack, coalesced stores.
// EPI 1 (gemm2): out[b][tok][col] = acc + bias  (fp32 scatter, 64B/16-lane lines).
template<int BM, int KD, int EPI>
__global__ __launch_bounds__(512, 2) void gemm_8ph_kernel(
    const u16* __restrict__ A, const u16* __restrict__ Bm,
    const float* __restrict__ bias, u16* __restrict__ hout,
    float* __restrict__ outp, const int* __restrict__ idxg, int row0)
{
    constexpr int BN    = 256;
    constexpr int NT    = KD / 64;            // K-tiles
    constexpr int M_REP = BM / 32;            // m-frags per wave
    constexpr int PH    = (BM == 256) ? 8 : 4;// phases per 2 K-tiles
    constexpr int SPP   = 8 / PH;             // stage half-tiles per phase
    constexpr int IFL   = BM / 128 + 2;       // loads in flight at K-tile boundary

    __shared__ u16 SH[(BM + BN) * 128];
    u16* SA = SH;
    u16* SB = SH + BM * 128;

    const int tid  = threadIdx.x;
    const int lane = tid & 63;
    const int wid  = tid >> 6;
    const int wm = wid >> 2, wn = wid & 3;
    const int fr = lane & 15;
    const int cq = lane >> 4;                 // k-chunk of this lane's fragment
    const int rq = cq * 4;

    constexpr int gx = (EPI == 0 ? DFF_ : D_) / 256;
    const int nwg = gridDim.x;
    const int o   = blockIdx.x;
    const int swz = (o & 7) * (nwg >> 3) + (o >> 3);
    const int bn  = (swz % gx) * 256;
    const int bm  = (swz / gx) * BM;

    // chunk-major staging: lds slot idx = c*ROWS + row  (linear dst = tid*8 elems;
    // second gload covers idx tid+512 -> chunk c+2, same row -> global src +16 elems)
    const int rowA = tid % BM,  cA = tid / BM;
    const int rowB = tid & 255, cB = tid >> 8;
    const u16* AbaseS = A  + (size_t)(bm + rowA) * KD + cA * 8;
    const u16* BbaseS = Bm + (size_t)(bn + rowB) * KD + cB * 8;

    f32x4 acc[M_REP][4];
    #pragma unroll
    for (int m = 0; m < M_REP; ++m)
        #pragma unroll
        for (int n = 0; n < 4; ++n) acc[m][n] = (f32x4)0.0f;

    // stage half-tile s: kt=s>>2, j=s&3 {0:Ak0,1:Bk0,2:Ak1,3:Bk1}
    auto stage = [&](int s) {
        int kt = s >> 2, j = s & 3;
        int d = kt & 1, h = j >> 1;
        int koff = kt * 64 + h * 32;
        if (j & 1) {
            u16* dst = SB + (d * 2 + h) * 8192 + tid * 8;
            gload_lds16(BbaseS + koff, dst);
            gload_lds16(BbaseS + koff + 16, dst + 4096);
        } else {
            u16* dst = SA + (d * 2 + h) * (BM * 32) + tid * 8;
            gload_lds16(AbaseS + koff, dst);
            if constexpr (BM == 256)
                gload_lds16(AbaseS + koff + 16, dst + 4096);
        }
    };

    #pragma unroll
    for (int s = 0; s < 6; ++s) stage(s);
    wait_vm<IFL>();
    __builtin_amdgcn_s_barrier();

    bf16x8 bfv[4];
    for (int i = 0; i < NT / 2; ++i) {
        #pragma unroll
        for (int p = 0; p < PH; ++p) {
            const int d   = (BM == 256) ? ((p >> 2) & 1) : ((p >> 1) & 1);
            const int kh  = (BM == 256) ? ((p >> 1) & 1) : (p & 1);
            const int mlo = (BM == 256) ? (p & 1) * 4 : 0;
            const bool readB = (BM == 128) || ((p & 1) == 0);
            const int slot = d * 2 + kh;
            if (readB) {
                #pragma unroll
                for (int n = 0; n < 4; ++n)
                    bfv[n] = *(const bf16x8*)(SB + slot * 8192 + cq * 2048 +
                              (wn * 64 + n * 16 + fr) * 8);
            }
            bf16x8 af[4];
            #pragma unroll
            for (int q = 0; q < 4; ++q)
                af[q] = *(const bf16x8*)(SA + slot * (BM * 32) + cq * (BM * 8) +
                          (wm * (BM / 2) + (mlo + q) * 16 + fr) * 8);
            #pragma unroll
            for (int u = 0; u < SPP; ++u) {
                int s = 8 * i + SPP * p + 6 + u;
                if (s < 4 * NT) stage(s);
            }
            __builtin_amdgcn_s_barrier();
            asm volatile("s_waitcnt lgkmcnt(0)" ::: "memory");
            __builtin_amdgcn_sched_barrier(0);
            __builtin_amdgcn_s_setprio(1);
            #pragma unroll
            for (int q = 0; q < 4; ++q)
                #pragma unroll
                for (int n = 0; n < 4; ++n)
                    acc[mlo + q][n] = __builtin_amdgcn_mfma_f32_16x16x32_bf16(
                        af[q], bfv[n], acc[mlo + q][n], 0, 0, 0);
            __builtin_amdgcn_s_setprio(0);
            if (p == PH / 2 - 1) {
                if (i == NT / 2 - 1) wait_vm<0>(); else wait_vm<IFL>();
            } else if (p == PH - 1) {
                if (i < NT / 2 - 1) wait_vm<IFL>();
            }
            __builtin_amdgcn_s_barrier();
        }
    }

    if constexpr (EPI == 0) {
        u16* ct = SH;                          // [256][256] bf16 = 128 KiB
        #pragma unroll
        for (int n = 0; n < 4; ++n) {
            const int col = wn * 64 + n * 16 + fr;
            const float bc = bias[bn + col];
            #pragma unroll
            for (int m = 0; m < M_REP; ++m) {
                const int rb = wm * (BM / 2) + m * 16 + rq;
                #pragma unroll
                for (int r = 0; r < 4; ++r) {
                    int row = rb + r;
                    int pc  = col ^ (((row >> 2) & 3) << 4);   // bank spread
                    ct[row * 256 + pc] = f2bf(gelu_fast(acc[m][n][r] + bc));
                }
            }
        }
        __syncthreads();
        const int chunk = tid & 31;
        const int rw    = tid >> 5;
        #pragma unroll
        for (int pass = 0; pass < 16; ++pass) {
            int row = pass * 16 + rw;
            int pb  = (chunk * 8) ^ (((row >> 2) & 3) << 4);
            bf16x8 v = *(const bf16x8*)(ct + row * 256 + pb);
            *(bf16x8*)(hout + (size_t)(bm + row) * DFF_ + bn + chunk * 8) = v;
        }
    } else {
        #pragma unroll
        for (int n = 0; n < 4; ++n) {
            const int col = bn + wn * 64 + n * 16 + fr;
            const float bc = bias[col];
            #pragma unroll
            for (int m = 0; m < M_REP; ++m) {
                const int rbase = bm + wm * (BM / 2) + m * 16 + rq;
                #pragma unroll
                for (int r = 0; r < 4; ++r) {
                    int grow = row0 + rbase + r;
                    int bb = grow >> 11;
                    int tok = idxg[grow];
                    outp[((size_t)bb * L_ + (size_t)tok) * D_ + col] =
                        acc[m][n][r] + bc;
                }
            }
        }
    }
}

extern "C" void kernel_launch(void* const* d_in, const int* in_sizes, int n_in,
                              void* d_out, int out_size, void* d_ws, size_t ws_size,
                              hipStream_t stream)
{
    const float* x  = (const float*)d_in[0];
    const float* W1 = (const float*)d_in[1];
    const float* b1 = (const float*)d_in[2];
    const float* W2 = (const float*)d_in[3];
    const float* b2 = (const float*)d_in[4];
    const float* wr = (const float*)d_in[5];
    const float* br = (const float*)d_in[6];
    float* out = (float*)d_out;

    char* ws = (char*)d_ws;
    int*   idx    = (int*)ws;                          // 32 KB
    float* scores = (float*)(ws + (32 << 10));         // 64 KB
    int*   sel    = (int*)(ws + (96 << 10));           // 64 KB
    u16* W1T = (u16*)(ws + (256 << 10));               // [4096][1024] bf16, 8 MB
    u16* W2T = W1T + (size_t)DFF_ * D_;                // [1024][4096] bf16, 8 MB

    size_t fixedB = (size_t)(256 << 10) + (size_t)DFF_ * D_ * 2 * 2;
    size_t avail  = ws_size > fixedB ? ws_size - fixedB : 0;
    int RC = (int)(avail / (size_t)(D_ * 2 + DFF_ * 2));
    RC = (RC / 256) * 256;
    if (RC > B_ * K_) RC = B_ * K_;
    if (RC < 256) RC = 256;
    u16* xsel = (u16*)(ws + fixedB);                   // [RC][1024] bf16
    u16* hbuf = xsel + (size_t)RC * D_;                // [RC][4096] bf16

    prep_kernel<<<dim3(12288), 256, 0, stream>>>(x, wr, br, scores, W1, W2, W1T, W2T);
    rank_zero_kernel<<<dim3(L_ / 64, B_), 256, 0, stream>>>(scores, sel, out);
    compact_kernel<<<dim3(B_), 256, 0, stream>>>(sel, idx);

    for (int r0 = 0; r0 < B_ * K_; r0 += RC) {
        int rc = (B_ * K_ - r0 < RC) ? (B_ * K_ - r0) : RC;
        gather_bf16_kernel<<<dim3(rc), 256, 0, stream>>>(x, idx, r0, xsel);
        gemm_8ph_kernel<256, D_, 0><<<dim3((DFF_ / 256) * (rc / 256)), 512, 0, stream>>>(
            xsel, W1T, b1, hbuf, nullptr, nullptr, 0);
        gemm_8ph_kernel<128, DFF_, 1><<<dim3((D_ / 256) * (rc / 128)), 512, 0, stream>>>(
            hbuf, W2T, b2, nullptr, out, idx, r0);
    }
}

// Round 8
// 215.637 us; speedup vs baseline: 1.3872x; 1.3872x over previous
//
#include <hip/hip_runtime.h>
#include <hip/hip_bf16.h>

#define B_   4
#define L_   4096
#define D_   1024
#define DFF_ 4096
#define K_   2048

typedef __attribute__((ext_vector_type(8))) short bf16x8;
typedef __attribute__((ext_vector_type(4))) float f32x4;
typedef unsigned short u16;

__device__ __forceinline__ u16 f2bf(float f) {
    unsigned u = __float_as_uint(f);
    u += 0x7fffu + ((u >> 16) & 1u);          // round-to-nearest-even
    return (u16)(u >> 16);
}

__device__ __forceinline__ float gelu_fast(float v) {
    float z = 1.5957691216057308f * v * (1.0f + 0.044715f * v * v);
    float e = __builtin_amdgcn_exp2f(-1.4426950408889634f * z);
    return v * __builtin_amdgcn_rcpf(1.0f + e);
}

__device__ __forceinline__ void gload_lds16(const void* g, void* l) {
    __builtin_amdgcn_global_load_lds(
        (const __attribute__((address_space(1))) void*)g,
        (__attribute__((address_space(3))) void*)l, 16, 0, 0);
}

template<int N> __device__ __forceinline__ void wait_vm() {
    if constexpr (N == 0) asm volatile("s_waitcnt vmcnt(0)" ::: "memory");
    else if constexpr (N == 3) asm volatile("s_waitcnt vmcnt(3)" ::: "memory");
    else if constexpr (N == 4) asm volatile("s_waitcnt vmcnt(4)" ::: "memory");
    __builtin_amdgcn_sched_barrier(0);
}

// ============ fused prep: score (blocks 0..4095) + W1 transpose (4096..8191)
// ============             + W2 transpose (8192..12287)
__global__ __launch_bounds__(256) void prep_kernel(
    const float* __restrict__ x, const float* __restrict__ wr,
    const float* __restrict__ br, float* __restrict__ scores,
    const float* __restrict__ W1, const float* __restrict__ W2,
    u16* __restrict__ W1T, u16* __restrict__ W2T)
{
    __shared__ float t[32][33];
    const int bb = blockIdx.x;
    if (bb < 4096) {
        int gtid  = bb * 256 + threadIdx.x;
        int token = gtid >> 6;
        int lane  = threadIdx.x & 63;
        const float* xr = x + (size_t)token * D_;
        double acc = 0.0;
        #pragma unroll
        for (int i = 0; i < 4; ++i) {
            int off = (lane + i * 64) * 4;
            float4 xv = *(const float4*)(xr + off);
            float4 wv = *(const float4*)(wr + off);
            acc += (double)xv.x * wv.x + (double)xv.y * wv.y +
                   (double)xv.z * wv.z + (double)xv.w * wv.w;
        }
        #pragma unroll
        for (int off = 32; off > 0; off >>= 1)
            acc += __shfl_down(acc, off);
        if (lane == 0) scores[token] = (float)(acc + (double)br[0]);
        return;
    }
    const float* in; u16* outb; int RK, RN, bx, by;
    if (bb < 8192) {
        int i = bb - 4096; in = W1; outb = W1T; RK = D_; RN = DFF_;
        bx = i & 127; by = i >> 7;
    } else {
        int i = bb - 8192; in = W2; outb = W2T; RK = DFF_; RN = D_;
        bx = i & 31; by = i >> 5;
    }
    int n0 = bx * 32, k0 = by * 32;
    int tx = threadIdx.x & 31, ty = threadIdx.x >> 5;
    #pragma unroll
    for (int i = 0; i < 4; ++i)
        t[ty + 8 * i][tx] = in[(size_t)(k0 + ty + 8 * i) * RN + (n0 + tx)];
    __syncthreads();
    #pragma unroll
    for (int i = 0; i < 4; ++i)
        outb[(size_t)(n0 + ty + 8 * i) * RK + (k0 + tx)] = f2bf(t[tx][ty + 8 * i]);
}

// ============ rank (exact top-k, jax tie-break) + zero unselected out rows
__global__ __launch_bounds__(256) void rank_zero_kernel(
    const float* __restrict__ scores, int* __restrict__ sel,
    float* __restrict__ out)
{
    __shared__ float sc[L_];
    __shared__ int selLds[64];
    const int b = blockIdx.y;
    const int t = threadIdx.x;
    const float* sb = scores + b * L_;
    for (int i = t; i < L_; i += 256) sc[i] = sb[i];
    __syncthreads();
    const int tg  = t >> 2;
    const int sub = t & 3;
    const int l   = blockIdx.x * 64 + tg;
    const float s = sc[l];
    int cnt = 0;
    const float4* sc4 = (const float4*)sc;
    const int base4 = sub * 256;
    for (int j4 = 0; j4 < 256; ++j4) {
        float4 v = sc4[base4 + j4];
        int j = (base4 + j4) * 4;
        cnt += (int)((v.x > s) || (v.x == s && (j + 0) < l));
        cnt += (int)((v.y > s) || (v.y == s && (j + 1) < l));
        cnt += (int)((v.z > s) || (v.z == s && (j + 2) < l));
        cnt += (int)((v.w > s) || (v.w == s && (j + 3) < l));
    }
    cnt += __shfl_xor(cnt, 1);
    cnt += __shfl_xor(cnt, 2);
    const int issel = (cnt < K_) ? 1 : 0;
    if (sub == 0) { sel[b * L_ + l] = issel; selLds[tg] = issel; }
    __syncthreads();
    float* obase = out + ((size_t)b * L_ + (size_t)blockIdx.x * 64) * D_;
    const float4 z = make_float4(0.f, 0.f, 0.f, 0.f);
    for (int r = 0; r < 64; ++r)
        if (!selLds[r])
            *(float4*)(obase + (size_t)r * D_ + t * 4) = z;
}

// ---------------- compact selected indices (ascending) ----------------
__global__ __launch_bounds__(256) void compact_kernel(
    const int* __restrict__ sel, int* __restrict__ idx)
{
    __shared__ int psum[256];
    int b = blockIdx.x, t = threadIdx.x;
    const int* sb = sel + b * L_;
    int base = t * 16;
    int flags[16]; int c = 0;
    #pragma unroll
    for (int i = 0; i < 16; ++i) { flags[i] = sb[base + i]; c += flags[i]; }
    psum[t] = c;
    __syncthreads();
    if (t == 0) {
        int acc = 0;
        for (int j = 0; j < 256; ++j) { int v = psum[j]; psum[j] = acc; acc += v; }
    }
    __syncthreads();
    int p = psum[t];
    #pragma unroll
    for (int i = 0; i < 16; ++i)
        if (flags[i]) idx[b * K_ + (p++)] = base + i;
}

// ---------------- gather selected rows, fp32->bf16 ----------------
__global__ __launch_bounds__(256) void gather_bf16_kernel(
    const float* __restrict__ x, const int* __restrict__ idxg,
    int row0, u16* __restrict__ xsel)
{
    int rl = blockIdx.x;
    int grow = row0 + rl;
    int tok = idxg[grow];
    int bb = grow >> 11;
    const float* src = x + ((size_t)bb * L_ + (size_t)tok) * D_;
    int t = threadIdx.x;
    float4 v = *(const float4*)(src + t * 4);
    ushort4 o;
    o.x = f2bf(v.x); o.y = f2bf(v.y); o.z = f2bf(v.z); o.w = f2bf(v.w);
    *(ushort4*)(xsel + (size_t)rl * D_ + t * 4) = o;
}

// =================== unified phase-pipelined MFMA GEMM (T2+T3+T4+T5) ===================
// BN = 256 fixed, 8 waves (2M x 4N). A: [M][KD] bf16. Bm: [N][KD] bf16 (n-major).
// LDS row-major [row][32] per slot, staged with COALESCED global reads (4 threads
// cover one row's 64B line) and an in-line XOR chunk permutation:
//   LDS[row][c] = glob[row][c ^ ((row>>1)&3)]
// Read side uses chunk cq ^ ((fr>>1)&3): quarter-wave lanes spread over 8 bank-start
// positions, every bank hit exactly 8x per wave b128 read -> conflict-free.
// BM=256: 8 phases / 2 K-tiles (16 MFMA each).  BM=128: 4 phases (16 MFMA each).
// EPI 0 (gemm1): h = bf16(gelu(acc+bias)) via LDS C-tile repack, coalesced stores.
// EPI 1 (gemm2): out[b][tok][col] = acc + bias  (fp32 scatter, 64B/16-lane lines).
template<int BM, int KD, int EPI>
__global__ __launch_bounds__(512, 2) void gemm_8ph_kernel(
    const u16* __restrict__ A, const u16* __restrict__ Bm,
    const float* __restrict__ bias, u16* __restrict__ hout,
    float* __restrict__ outp, const int* __restrict__ idxg, int row0)
{
    constexpr int BN    = 256;
    constexpr int NT    = KD / 64;            // K-tiles
    constexpr int M_REP = BM / 32;            // m-frags per wave
    constexpr int PH    = (BM == 256) ? 8 : 4;// phases per 2 K-tiles
    constexpr int SPP   = 8 / PH;             // stage half-tiles per phase
    constexpr int IFL   = BM / 128 + 2;       // loads in flight at K-tile boundary

    __shared__ u16 SH[(BM + BN) * 128];
    u16* SA = SH;
    u16* SB = SH + BM * 128;

    const int tid  = threadIdx.x;
    const int lane = tid & 63;
    const int wid  = tid >> 6;
    const int wm = wid >> 2, wn = wid & 3;
    const int fr = lane & 15;
    const int cq = lane >> 4;                 // k-chunk of this lane's fragment
    const int rq = cq * 4;
    const int kqx = (cq ^ ((fr >> 1) & 3)) * 8;   // XOR'd chunk elem-offset for reads

    constexpr int gx = (EPI == 0 ? DFF_ : D_) / 256;
    const int nwg = gridDim.x;
    const int o   = blockIdx.x;
    const int swz = (o & 7) * (nwg >> 3) + (o >> 3);
    const int bn  = (swz % gx) * 256;
    const int bm  = (swz / gx) * BM;

    // staging: thread tid -> row tid>>2, lds-chunk tid&3; global source chunk XOR'd
    // (permutation stays inside the row's 64B line -> coalescing preserved)
    const int srow = tid >> 2;                // 0..127
    const int sc   = tid & 3;
    const int scg  = sc ^ ((srow >> 1) & 3);
    const u16* AbaseS = A  + (size_t)(bm + srow) * KD + scg * 8;
    const u16* BbaseS = Bm + (size_t)(bn + srow) * KD + scg * 8;

    f32x4 acc[M_REP][4];
    #pragma unroll
    for (int m = 0; m < M_REP; ++m)
        #pragma unroll
        for (int n = 0; n < 4; ++n) acc[m][n] = (f32x4)0.0f;

    // stage half-tile s: kt=s>>2, j=s&3 {0:Ak0,1:Bk0,2:Ak1,3:Bk1}
    auto stage = [&](int s) {
        int kt = s >> 2, j = s & 3;
        int d = kt & 1, h = j >> 1;
        int koff = kt * 64 + h * 32;
        if (j & 1) {
            u16* dst = SB + (d * 2 + h) * 8192 + tid * 8;
            gload_lds16(BbaseS + koff, dst);
            gload_lds16(BbaseS + koff + (size_t)128 * KD, dst + 4096);
        } else {
            u16* dst = SA + (d * 2 + h) * (BM * 32) + tid * 8;
            gload_lds16(AbaseS + koff, dst);
            if constexpr (BM == 256)
                gload_lds16(AbaseS + koff + (size_t)128 * KD, dst + 4096);
        }
    };

    #pragma unroll
    for (int s = 0; s < 6; ++s) stage(s);
    wait_vm<IFL>();
    __builtin_amdgcn_s_barrier();

    bf16x8 bfv[4];
    for (int i = 0; i < NT / 2; ++i) {
        #pragma unroll
        for (int p = 0; p < PH; ++p) {
            const int d   = (BM == 256) ? ((p >> 2) & 1) : ((p >> 1) & 1);
            const int kh  = (BM == 256) ? ((p >> 1) & 1) : (p & 1);
            const int mlo = (BM == 256) ? (p & 1) * 4 : 0;
            const bool readB = (BM == 128) || ((p & 1) == 0);
            const int slot = d * 2 + kh;
            if (readB) {
                #pragma unroll
                for (int n = 0; n < 4; ++n)
                    bfv[n] = *(const bf16x8*)(SB + slot * 8192 +
                              (wn * 64 + n * 16 + fr) * 32 + kqx);
            }
            bf16x8 af[4];
            #pragma unroll
            for (int q = 0; q < 4; ++q)
                af[q] = *(const bf16x8*)(SA + slot * (BM * 32) +
                          (wm * (BM / 2) + (mlo + q) * 16 + fr) * 32 + kqx);
            #pragma unroll
            for (int u = 0; u < SPP; ++u) {
                int s = 8 * i + SPP * p + 6 + u;
                if (s < 4 * NT) stage(s);
            }
            __builtin_amdgcn_s_barrier();
            asm volatile("s_waitcnt lgkmcnt(0)" ::: "memory");
            __builtin_amdgcn_sched_barrier(0);
            __builtin_amdgcn_s_setprio(1);
            #pragma unroll
            for (int q = 0; q < 4; ++q)
                #pragma unroll
                for (int n = 0; n < 4; ++n)
                    acc[mlo + q][n] = __builtin_amdgcn_mfma_f32_16x16x32_bf16(
                        af[q], bfv[n], acc[mlo + q][n], 0, 0, 0);
            __builtin_amdgcn_s_setprio(0);
            if (p == PH / 2 - 1) {
                if (i == NT / 2 - 1) wait_vm<0>(); else wait_vm<IFL>();
            } else if (p == PH - 1) {
                if (i < NT / 2 - 1) wait_vm<IFL>();
            }
            __builtin_amdgcn_s_barrier();
        }
    }

    if constexpr (EPI == 0) {
        u16* ct = SH;                          // [256][256] bf16 = 128 KiB
        #pragma unroll
        for (int n = 0; n < 4; ++n) {
            const int col = wn * 64 + n * 16 + fr;
            const float bc = bias[bn + col];
            #pragma unroll
            for (int m = 0; m < M_REP; ++m) {
                const int rb = wm * (BM / 2) + m * 16 + rq;
                #pragma unroll
                for (int r = 0; r < 4; ++r) {
                    int row = rb + r;
                    int pc  = col ^ (((row >> 2) & 3) << 4);   // bank spread
                    ct[row * 256 + pc] = f2bf(gelu_fast(acc[m][n][r] + bc));
                }
            }
        }
        __syncthreads();
        const int chunk = tid & 31;
        const int rw    = tid >> 5;
        #pragma unroll
        for (int pass = 0; pass < 16; ++pass) {
            int row = pass * 16 + rw;
            int pb  = (chunk * 8) ^ (((row >> 2) & 3) << 4);
            bf16x8 v = *(const bf16x8*)(ct + row * 256 + pb);
            *(bf16x8*)(hout + (size_t)(bm + row) * DFF_ + bn + chunk * 8) = v;
        }
    } else {
        #pragma unroll
        for (int n = 0; n < 4; ++n) {
            const int col = bn + wn * 64 + n * 16 + fr;
            const float bc = bias[col];
            #pragma unroll
            for (int m = 0; m < M_REP; ++m) {
                const int rbase = bm + wm * (BM / 2) + m * 16 + rq;
                #pragma unroll
                for (int r = 0; r < 4; ++r) {
                    int grow = row0 + rbase + r;
                    int bb = grow >> 11;
                    int tok = idxg[grow];
                    outp[((size_t)bb * L_ + (size_t)tok) * D_ + col] =
                        acc[m][n][r] + bc;
                }
            }
        }
    }
}

extern "C" void kernel_launch(void* const* d_in, const int* in_sizes, int n_in,
                              void* d_out, int out_size, void* d_ws, size_t ws_size,
                              hipStream_t stream)
{
    const float* x  = (const float*)d_in[0];
    const float* W1 = (const float*)d_in[1];
    const float* b1 = (const float*)d_in[2];
    const float* W2 = (const float*)d_in[3];
    const float* b2 = (const float*)d_in[4];
    const float* wr = (const float*)d_in[5];
    const float* br = (const float*)d_in[6];
    float* out = (float*)d_out;

    char* ws = (char*)d_ws;
    int*   idx    = (int*)ws;                          // 32 KB
    float* scores = (float*)(ws + (32 << 10));         // 64 KB
    int*   sel    = (int*)(ws + (96 << 10));           // 64 KB
    u16* W1T = (u16*)(ws + (256 << 10));               // [4096][1024] bf16, 8 MB
    u16* W2T = W1T + (size_t)DFF_ * D_;                // [1024][4096] bf16, 8 MB

    size_t fixedB = (size_t)(256 << 10) + (size_t)DFF_ * D_ * 2 * 2;
    size_t avail  = ws_size > fixedB ? ws_size - fixedB : 0;
    int RC = (int)(avail / (size_t)(D_ * 2 + DFF_ * 2));
    RC = (RC / 256) * 256;
    if (RC > B_ * K_) RC = B_ * K_;
    if (RC < 256) RC = 256;
    u16* xsel = (u16*)(ws + fixedB);                   // [RC][1024] bf16
    u16* hbuf = xsel + (size_t)RC * D_;                // [RC][4096] bf16

    prep_kernel<<<dim3(12288), 256, 0, stream>>>(x, wr, br, scores, W1, W2, W1T, W2T);
    rank_zero_kernel<<<dim3(L_ / 64, B_), 256, 0, stream>>>(scores, sel, out);
    compact_kernel<<<dim3(B_), 256, 0, stream>>>(sel, idx);

    for (int r0 = 0; r0 < B_ * K_; r0 += RC) {
        int rc = (B_ * K_ - r0 < RC) ? (B_ * K_ - r0) : RC;
        gather_bf16_kernel<<<dim3(rc), 256, 0, stream>>>(x, idx, r0, xsel);
        gemm_8ph_kernel<256, D_, 0><<<dim3((DFF_ / 256) * (rc / 256)), 512, 0, stream>>>(
            xsel, W1T, b1, hbuf, nullptr, nullptr, 0);
        gemm_8ph_kernel<128, DFF_, 1><<<dim3((D_ / 256) * (rc / 128)), 512, 0, stream>>>(
            hbuf, W2T, b2, nullptr, out, idx, r0);
    }
}

// Round 9
// 214.145 us; speedup vs baseline: 1.3968x; 1.0070x over previous
//
#include <hip/hip_runtime.h>
#include <hip/hip_bf16.h>

#define B_   4
#define L_   4096
#define D_   1024
#define DFF_ 4096
#define K_   2048

typedef __attribute__((ext_vector_type(8))) short bf16x8;
typedef __attribute__((ext_vector_type(4))) float f32x4;
typedef unsigned short u16;

__device__ __forceinline__ u16 f2bf(float f) {
    unsigned u = __float_as_uint(f);
    u += 0x7fffu + ((u >> 16) & 1u);          // round-to-nearest-even
    return (u16)(u >> 16);
}

__device__ __forceinline__ float gelu_fast(float v) {
    float z = 1.5957691216057308f * v * (1.0f + 0.044715f * v * v);
    float e = __builtin_amdgcn_exp2f(-1.4426950408889634f * z);
    return v * __builtin_amdgcn_rcpf(1.0f + e);
}

__device__ __forceinline__ void gload_lds16(const void* g, void* l) {
    __builtin_amdgcn_global_load_lds(
        (const __attribute__((address_space(1))) void*)g,
        (__attribute__((address_space(3))) void*)l, 16, 0, 0);
}

template<int N> __device__ __forceinline__ void wait_vm() {
    if constexpr (N == 0) asm volatile("s_waitcnt vmcnt(0)" ::: "memory");
    else if constexpr (N == 3) asm volatile("s_waitcnt vmcnt(3)" ::: "memory");
    else if constexpr (N == 4) asm volatile("s_waitcnt vmcnt(4)" ::: "memory");
    else if constexpr (N == 6) asm volatile("s_waitcnt vmcnt(6)" ::: "memory");
    else if constexpr (N == 8) asm volatile("s_waitcnt vmcnt(8)" ::: "memory");
    __builtin_amdgcn_sched_barrier(0);
}

template<int N> __device__ __forceinline__ void wait_lgkm() {
    if constexpr (N == 4) asm volatile("s_waitcnt lgkmcnt(4)" ::: "memory");
    else                  asm volatile("s_waitcnt lgkmcnt(8)" ::: "memory");
    __builtin_amdgcn_sched_barrier(0);
}

// ============ fused prep: score (blocks 0..4095) + W1 transpose (4096..8191)
// ============             + W2 transpose (8192..12287)
__global__ __launch_bounds__(256) void prep_kernel(
    const float* __restrict__ x, const float* __restrict__ wr,
    const float* __restrict__ br, float* __restrict__ scores,
    const float* __restrict__ W1, const float* __restrict__ W2,
    u16* __restrict__ W1T, u16* __restrict__ W2T)
{
    __shared__ float t[32][33];
    const int bb = blockIdx.x;
    if (bb < 4096) {
        int gtid  = bb * 256 + threadIdx.x;
        int token = gtid >> 6;
        int lane  = threadIdx.x & 63;
        const float* xr = x + (size_t)token * D_;
        double acc = 0.0;
        #pragma unroll
        for (int i = 0; i < 4; ++i) {
            int off = (lane + i * 64) * 4;
            float4 xv = *(const float4*)(xr + off);
            float4 wv = *(const float4*)(wr + off);
            acc += (double)xv.x * wv.x + (double)xv.y * wv.y +
                   (double)xv.z * wv.z + (double)xv.w * wv.w;
        }
        #pragma unroll
        for (int off = 32; off > 0; off >>= 1)
            acc += __shfl_down(acc, off);
        if (lane == 0) scores[token] = (float)(acc + (double)br[0]);
        return;
    }
    const float* in; u16* outb; int RK, RN, bx, by;
    if (bb < 8192) {
        int i = bb - 4096; in = W1; outb = W1T; RK = D_; RN = DFF_;
        bx = i & 127; by = i >> 7;
    } else {
        int i = bb - 8192; in = W2; outb = W2T; RK = DFF_; RN = D_;
        bx = i & 31; by = i >> 5;
    }
    int n0 = bx * 32, k0 = by * 32;
    int tx = threadIdx.x & 31, ty = threadIdx.x >> 5;
    #pragma unroll
    for (int i = 0; i < 4; ++i)
        t[ty + 8 * i][tx] = in[(size_t)(k0 + ty + 8 * i) * RN + (n0 + tx)];
    __syncthreads();
    #pragma unroll
    for (int i = 0; i < 4; ++i)
        outb[(size_t)(n0 + ty + 8 * i) * RK + (k0 + tx)] = f2bf(t[tx][ty + 8 * i]);
}

// ============ rank (exact top-k, jax tie-break) + zero unselected out rows
__global__ __launch_bounds__(256) void rank_zero_kernel(
    const float* __restrict__ scores, int* __restrict__ sel,
    float* __restrict__ out)
{
    __shared__ float sc[L_];
    __shared__ int selLds[64];
    const int b = blockIdx.y;
    const int t = threadIdx.x;
    const float* sb = scores + b * L_;
    for (int i = t; i < L_; i += 256) sc[i] = sb[i];
    __syncthreads();
    const int tg  = t >> 2;
    const int sub = t & 3;
    const int l   = blockIdx.x * 64 + tg;
    const float s = sc[l];
    int cnt = 0;
    const float4* sc4 = (const float4*)sc;
    const int base4 = sub * 256;
    for (int j4 = 0; j4 < 256; ++j4) {
        float4 v = sc4[base4 + j4];
        int j = (base4 + j4) * 4;
        cnt += (int)((v.x > s) || (v.x == s && (j + 0) < l));
        cnt += (int)((v.y > s) || (v.y == s && (j + 1) < l));
        cnt += (int)((v.z > s) || (v.z == s && (j + 2) < l));
        cnt += (int)((v.w > s) || (v.w == s && (j + 3) < l));
    }
    cnt += __shfl_xor(cnt, 1);
    cnt += __shfl_xor(cnt, 2);
    const int issel = (cnt < K_) ? 1 : 0;
    if (sub == 0) { sel[b * L_ + l] = issel; selLds[tg] = issel; }
    __syncthreads();
    float* obase = out + ((size_t)b * L_ + (size_t)blockIdx.x * 64) * D_;
    const float4 z = make_float4(0.f, 0.f, 0.f, 0.f);
    for (int r = 0; r < 64; ++r)
        if (!selLds[r])
            *(float4*)(obase + (size_t)r * D_ + t * 4) = z;
}

// ---------------- compact selected indices (ascending) ----------------
__global__ __launch_bounds__(256) void compact_kernel(
    const int* __restrict__ sel, int* __restrict__ idx)
{
    __shared__ int psum[256];
    int b = blockIdx.x, t = threadIdx.x;
    const int* sb = sel + b * L_;
    int base = t * 16;
    int flags[16]; int c = 0;
    #pragma unroll
    for (int i = 0; i < 16; ++i) { flags[i] = sb[base + i]; c += flags[i]; }
    psum[t] = c;
    __syncthreads();
    if (t == 0) {
        int acc = 0;
        for (int j = 0; j < 256; ++j) { int v = psum[j]; psum[j] = acc; acc += v; }
    }
    __syncthreads();
    int p = psum[t];
    #pragma unroll
    for (int i = 0; i < 16; ++i)
        if (flags[i]) idx[b * K_ + (p++)] = base + i;
}

// ---------------- gather selected rows, fp32->bf16 ----------------
__global__ __launch_bounds__(256) void gather_bf16_kernel(
    const float* __restrict__ x, const int* __restrict__ idxg,
    int row0, u16* __restrict__ xsel)
{
    int rl = blockIdx.x;
    int grow = row0 + rl;
    int tok = idxg[grow];
    int bb = grow >> 11;
    const float* src = x + ((size_t)bb * L_ + (size_t)tok) * D_;
    int t = threadIdx.x;
    float4 v = *(const float4*)(src + t * 4);
    ushort4 o;
    o.x = f2bf(v.x); o.y = f2bf(v.y); o.z = f2bf(v.z); o.w = f2bf(v.w);
    *(ushort4*)(xsel + (size_t)rl * D_ + t * 4) = o;
}

// ============== phase-pipelined MFMA GEMM, register-double-buffered fragments ==============
// BN = 256, 8 waves (2M x 4N). A: [M][KD] bf16. Bm: [N][KD] bf16 (n-major).
// LDS layout + XOR-within-line swizzle identical to round 8 (0 bank conflicts, coalesced).
// NEW: phase p issues ds_reads for phase p+1 into alternate regs, then waits counted
// lgkmcnt(N) (N = reads just issued) before MFMA_p -> LDS read burst overlaps MFMA pipe.
// ONE barrier per phase. vm-wait schedule re-derived (see comments).
// EPI 0 (gemm1): h = bf16(gelu(acc+bias)) via LDS C-tile repack, coalesced stores.
// EPI 1 (gemm2): out[b][tok][col] = acc + bias  (fp32 scatter, 64B/16-lane lines).
template<int BM, int KD, int EPI>
__global__ __launch_bounds__(512, 2) void gemm_8ph_kernel(
    const u16* __restrict__ A, const u16* __restrict__ Bm,
    const float* __restrict__ bias, u16* __restrict__ hout,
    float* __restrict__ outp, const int* __restrict__ idxg, int row0)
{
    constexpr int BN    = 256;
    constexpr int NT    = KD / 64;            // K-tiles
    constexpr int NI    = NT / 2;             // iterations (2 K-tiles each)
    constexpr int M_REP = BM / 32;            // m-frags per wave
    constexpr int PH    = (BM == 256) ? 8 : 4;// phases per 2 K-tiles
    constexpr int SPP   = 8 / PH;             // stage half-tiles per phase

    __shared__ u16 SH[(BM + BN) * 128];
    u16* SA = SH;
    u16* SB = SH + BM * 128;

    const int tid  = threadIdx.x;
    const int lane = tid & 63;
    const int wid  = tid >> 6;
    const int wm = wid >> 2, wn = wid & 3;
    const int fr = lane & 15;
    const int cq = lane >> 4;
    const int rq = cq * 4;
    const int kqx = (cq ^ ((fr >> 1) & 3)) * 8;   // XOR'd chunk elem-offset for reads

    constexpr int gx = (EPI == 0 ? DFF_ : D_) / 256;
    const int nwg = gridDim.x;
    const int o   = blockIdx.x;
    const int swz = (o & 7) * (nwg >> 3) + (o >> 3);
    const int bn  = (swz % gx) * 256;
    const int bm  = (swz / gx) * BM;

    // staging: thread tid -> row tid>>2, lds-chunk tid&3; global source chunk XOR'd
    const int srow = tid >> 2;
    const int sc   = tid & 3;
    const int scg  = sc ^ ((srow >> 1) & 3);
    const u16* AbaseS = A  + (size_t)(bm + srow) * KD + scg * 8;
    const u16* BbaseS = Bm + (size_t)(bn + srow) * KD + scg * 8;

    f32x4 acc[M_REP][4];
    #pragma unroll
    for (int m = 0; m < M_REP; ++m)
        #pragma unroll
        for (int n = 0; n < 4; ++n) acc[m][n] = (f32x4)0.0f;

    bf16x8 af[2][4];
    bf16x8 bfv[2][4];

    // stage half-tile s: kt=s>>2, j=s&3 {0:Ak0,1:Bk0,2:Ak1,3:Bk1}
    auto stage = [&](int s) {
        int kt = s >> 2, j = s & 3;
        int d = kt & 1, h = j >> 1;
        int koff = kt * 64 + h * 32;
        if (j & 1) {
            u16* dst = SB + (d * 2 + h) * 8192 + tid * 8;
            gload_lds16(BbaseS + koff, dst);
            gload_lds16(BbaseS + koff + (size_t)128 * KD, dst + 4096);
        } else {
            u16* dst = SA + (d * 2 + h) * (BM * 32) + tid * 8;
            gload_lds16(AbaseS + koff, dst);
            if constexpr (BM == 256)
                gload_lds16(AbaseS + koff + (size_t)128 * KD, dst + 4096);
        }
    };

    // prologue: stage halves 0..5; wait so halves 0,1 (kt0 kh0) are complete
    #pragma unroll
    for (int s = 0; s < 6; ++s) stage(s);
    if constexpr (BM == 256) wait_vm<8>(); else wait_vm<6>();
    __builtin_amdgcn_s_barrier();

// read fragments for phase q (q is a literal -> all reg indices constant-fold)
#define RDF(q) { \
    const int d_    = (PH == 8) ? (((q) >> 2) & 1) : (((q) >> 1) & 1); \
    const int kh_   = (PH == 8) ? (((q) >> 1) & 1) : ((q) & 1); \
    const int mlo_  = (PH == 8) ? ((q) & 1) * 4 : 0; \
    const int slot_ = d_ * 2 + kh_; \
    if (PH == 4 || ((q) & 1) == 0) { \
        const int bb_ = (PH == 8) ? (((q) >> 1) & 1) : ((q) & 1); \
        _Pragma("unroll") \
        for (int n = 0; n < 4; ++n) \
            bfv[bb_][n] = *(const bf16x8*)(SB + slot_ * 8192 + \
                          (wn * 64 + n * 16 + fr) * 32 + kqx); \
    } \
    _Pragma("unroll") \
    for (int q2 = 0; q2 < 4; ++q2) \
        af[(q) & 1][q2] = *(const bf16x8*)(SA + slot_ * (BM * 32) + \
                          (wm * (BM / 2) + (mlo_ + q2) * 16 + fr) * 32 + kqx); \
}

    RDF(0)

// one phase: stage -> reads(p+1) -> counted lgkm -> MFMA(p) -> vm-wait -> barrier
#define PHASE(p) { \
    _Pragma("unroll") \
    for (int u = 0; u < SPP; ++u) { \
        int s = 8 * i + SPP * (p) + 6 + u; \
        if (s < 4 * NT) stage(s); \
    } \
    RDF(((p) + 1) % PH) \
    if (PH == 4 || ((((p) + 1) % PH) & 1) == 0) wait_lgkm<8>(); else wait_lgkm<4>(); \
    __builtin_amdgcn_s_setprio(1); \
    { const int mlo_ = (PH == 8) ? ((p) & 1) * 4 : 0; \
      const int bi_  = (PH == 8) ? (((p) >> 1) & 1) : ((p) & 1); \
      _Pragma("unroll") \
      for (int q2 = 0; q2 < 4; ++q2) \
          _Pragma("unroll") \
          for (int n = 0; n < 4; ++n) \
              acc[mlo_ + q2][n] = __builtin_amdgcn_mfma_f32_16x16x32_bf16( \
                  af[(p) & 1][q2], bfv[bi_][n], acc[mlo_ + q2][n], 0, 0, 0); } \
    __builtin_amdgcn_s_setprio(0); \
    if constexpr (PH == 8) { \
        if ((p) == 2)      { if (lastI) wait_vm<4>(); else wait_vm<6>(); } \
        else if ((p) == 4) { if (lastI) wait_vm<0>(); else wait_vm<6>(); } \
        else                 wait_vm<6>(); \
    } else { \
        if ((p) == 0)        wait_vm<3>(); \
        else               { if (lastI) wait_vm<0>(); else wait_vm<3>(); } \
    } \
    __builtin_amdgcn_s_barrier(); \
}

    for (int i = 0; i < NI; ++i) {
        const bool lastI = (i == NI - 1);
        if constexpr (PH == 8) {
            PHASE(0) PHASE(1) PHASE(2) PHASE(3)
            PHASE(4) PHASE(5) PHASE(6) PHASE(7)
        } else {
            PHASE(0) PHASE(1) PHASE(2) PHASE(3)
        }
    }
#undef PHASE
#undef RDF

    if constexpr (EPI == 0) {
        u16* ct = SH;                          // [256][256] bf16 = 128 KiB
        #pragma unroll
        for (int n = 0; n < 4; ++n) {
            const int col = wn * 64 + n * 16 + fr;
            const float bc = bias[bn + col];
            #pragma unroll
            for (int m = 0; m < M_REP; ++m) {
                const int rb = wm * (BM / 2) + m * 16 + rq;
                #pragma unroll
                for (int r = 0; r < 4; ++r) {
                    int row = rb + r;
                    int pc  = col ^ (((row >> 2) & 3) << 4);   // bank spread
                    ct[row * 256 + pc] = f2bf(gelu_fast(acc[m][n][r] + bc));
                }
            }
        }
        __syncthreads();
        const int chunk = tid & 31;
        const int rw    = tid >> 5;
        #pragma unroll
        for (int pass = 0; pass < 16; ++pass) {
            int row = pass * 16 + rw;
            int pb  = (chunk * 8) ^ (((row >> 2) & 3) << 4);
            bf16x8 v = *(const bf16x8*)(ct + row * 256 + pb);
            *(bf16x8*)(hout + (size_t)(bm + row) * DFF_ + bn + chunk * 8) = v;
        }
    } else {
        #pragma unroll
        for (int n = 0; n < 4; ++n) {
            const int col = bn + wn * 64 + n * 16 + fr;
            const float bc = bias[col];
            #pragma unroll
            for (int m = 0; m < M_REP; ++m) {
                const int rbase = bm + wm * (BM / 2) + m * 16 + rq;
                #pragma unroll
                for (int r = 0; r < 4; ++r) {
                    int grow = row0 + rbase + r;
                    int bb = grow >> 11;
                    int tok = idxg[grow];
                    outp[((size_t)bb * L_ + (size_t)tok) * D_ + col] =
                        acc[m][n][r] + bc;
                }
            }
        }
    }
}

extern "C" void kernel_launch(void* const* d_in, const int* in_sizes, int n_in,
                              void* d_out, int out_size, void* d_ws, size_t ws_size,
                              hipStream_t stream)
{
    const float* x  = (const float*)d_in[0];
    const float* W1 = (const float*)d_in[1];
    const float* b1 = (const float*)d_in[2];
    const float* W2 = (const float*)d_in[3];
    const float* b2 = (const float*)d_in[4];
    const float* wr = (const float*)d_in[5];
    const float* br = (const float*)d_in[6];
    float* out = (float*)d_out;

    char* ws = (char*)d_ws;
    int*   idx    = (int*)ws;                          // 32 KB
    float* scores = (float*)(ws + (32 << 10));         // 64 KB
    int*   sel    = (int*)(ws + (96 << 10));           // 64 KB
    u16* W1T = (u16*)(ws + (256 << 10));               // [4096][1024] bf16, 8 MB
    u16* W2T = W1T + (size_t)DFF_ * D_;                // [1024][4096] bf16, 8 MB

    size_t fixedB = (size_t)(256 << 10) + (size_t)DFF_ * D_ * 2 * 2;
    size_t avail  = ws_size > fixedB ? ws_size - fixedB : 0;
    int RC = (int)(avail / (size_t)(D_ * 2 + DFF_ * 2));
    RC = (RC / 256) * 256;
    if (RC > B_ * K_) RC = B_ * K_;
    if (RC < 256) RC = 256;
    u16* xsel = (u16*)(ws + fixedB);                   // [RC][1024] bf16
    u16* hbuf = xsel + (size_t)RC * D_;                // [RC][4096] bf16

    prep_kernel<<<dim3(12288), 256, 0, stream>>>(x, wr, br, scores, W1, W2, W1T, W2T);
    rank_zero_kernel<<<dim3(L_ / 64, B_), 256, 0, stream>>>(scores, sel, out);
    compact_kernel<<<dim3(B_), 256, 0, stream>>>(sel, idx);

    for (int r0 = 0; r0 < B_ * K_; r0 += RC) {
        int rc = (B_ * K_ - r0 < RC) ? (B_ * K_ - r0) : RC;
        gather_bf16_kernel<<<dim3(rc), 256, 0, stream>>>(x, idx, r0, xsel);
        gemm_8ph_kernel<256, D_, 0><<<dim3((DFF_ / 256) * (rc / 256)), 512, 0, stream>>>(
            xsel, W1T, b1, hbuf, nullptr, nullptr, 0);
        gemm_8ph_kernel<128, DFF_, 1><<<dim3((D_ / 256) * (rc / 128)), 512, 0, stream>>>(
            hbuf, W2T, b2, nullptr, out, idx, r0);
    }
}